// Round 8
// baseline (1575.654 us; speedup 1.0000x reference)
//
#include <hip/hip_runtime.h>
#include <hip/hip_bf16.h>

#define NNODES 4096
#define NBATCH 4096
#define NBLK 8
#define LN_EPS 1e-5f

typedef __attribute__((ext_vector_type(8))) short short8;
typedef __attribute__((ext_vector_type(4))) float f32x4;
typedef __attribute__((ext_vector_type(4))) unsigned short u16x4;
typedef unsigned short u16;

__device__ __forceinline__ u16 bf16_rn(float f) {
  unsigned int u = __builtin_bit_cast(unsigned int, f);
  u += 0x7fffu + ((u >> 16) & 1u);
  return (u16)(u >> 16);
}

__device__ __forceinline__ float bf16_to_f(u16 h) {
  unsigned int u = ((unsigned int)h) << 16;
  return __builtin_bit_cast(float, u);
}

__device__ __forceinline__ void load_lds16(const void* g, void* l) {
  __builtin_amdgcn_global_load_lds((const __attribute__((address_space(1))) void*)g,
                                   (__attribute__((address_space(3))) void*)l,
                                   16, 0, 0);
}

// compiler-invisible 16B f32 load (keeps manual vmcnt counts exact)
__device__ __forceinline__ void gload4(f32x4& d, const float* p) {
  asm volatile("global_load_dwordx4 %0, %1, off" : "=&v"(d) : "v"(p) : "memory");
}

__device__ __forceinline__ short8 cvt8(f32x4 a, f32x4 b) {
  short8 r;
  r[0] = (short)bf16_rn(a[0]); r[1] = (short)bf16_rn(a[1]);
  r[2] = (short)bf16_rn(a[2]); r[3] = (short)bf16_rn(a[3]);
  r[4] = (short)bf16_rn(b[0]); r[5] = (short)bf16_rn(b[1]);
  r[6] = (short)bf16_rn(b[2]); r[7] = (short)bf16_rn(b[3]);
  return r;
}

// ---- row LayerNorm, f32 input (layer 0) -> bf16 out ----
__global__ __launch_bounds__(256) void ln_f32_kernel(const float* __restrict__ x,
                                                     const float* __restrict__ g,
                                                     const float* __restrict__ bt,
                                                     u16* __restrict__ out) {
  int row = blockIdx.x;
  int t = threadIdx.x;
  const float4* xr = (const float4*)(x + (size_t)row * NNODES);
  float4 v[4];
  float s = 0.f, ss = 0.f;
#pragma unroll
  for (int q = 0; q < 4; ++q) {
    v[q] = xr[q * 256 + t];
    s  += v[q].x + v[q].y + v[q].z + v[q].w;
    ss += v[q].x * v[q].x + v[q].y * v[q].y + v[q].z * v[q].z + v[q].w * v[q].w;
  }
#pragma unroll
  for (int off = 32; off >= 1; off >>= 1) {
    s  += __shfl_xor(s, off, 64);
    ss += __shfl_xor(ss, off, 64);
  }
  __shared__ float sh[8];
  int wid = t >> 6, lane = t & 63;
  if (lane == 0) { sh[wid] = s; sh[wid + 4] = ss; }
  __syncthreads();
  s  = sh[0] + sh[1] + sh[2] + sh[3];
  ss = sh[4] + sh[5] + sh[6] + sh[7];
  float mu  = s * (1.f / NNODES);
  float var = ss * (1.f / NNODES) - mu * mu;
  float rs  = rsqrtf(var + LN_EPS);
  u16x4* o = (u16x4*)(out + (size_t)row * NNODES);
  const float4* gv = (const float4*)g;
  const float4* bv = (const float4*)bt;
#pragma unroll
  for (int q = 0; q < 4; ++q) {
    int i = q * 256 + t;
    float4 gg = gv[i], bb = bv[i];
    u16x4 ov;
    ov[0] = bf16_rn((v[q].x - mu) * rs * gg.x + bb.x);
    ov[1] = bf16_rn((v[q].y - mu) * rs * gg.y + bb.y);
    ov[2] = bf16_rn((v[q].z - mu) * rs * gg.z + bb.z);
    ov[3] = bf16_rn((v[q].w - mu) * rs * gg.w + bb.w);
    o[i] = ov;
  }
}

// ---- row LayerNorm, bf16 input (layers 1..7) -> bf16 out ----
__global__ __launch_bounds__(256) void ln_bf16_kernel(const u16* __restrict__ x,
                                                      const float* __restrict__ g,
                                                      const float* __restrict__ bt,
                                                      u16* __restrict__ out) {
  int row = blockIdx.x;
  int t = threadIdx.x;
  const u16* xr = x + (size_t)row * NNODES;
  float f[2][8];
  float s = 0.f, ss = 0.f;
#pragma unroll
  for (int q = 0; q < 2; ++q) {
    short8 v = *(const short8*)(xr + q * 2048 + t * 8);
#pragma unroll
    for (int j = 0; j < 8; ++j) {
      float fv = bf16_to_f((u16)v[j]);
      f[q][j] = fv;
      s += fv; ss += fv * fv;
    }
  }
#pragma unroll
  for (int off = 32; off >= 1; off >>= 1) {
    s  += __shfl_xor(s, off, 64);
    ss += __shfl_xor(ss, off, 64);
  }
  __shared__ float sh[8];
  int wid = t >> 6, lane = t & 63;
  if (lane == 0) { sh[wid] = s; sh[wid + 4] = ss; }
  __syncthreads();
  s  = sh[0] + sh[1] + sh[2] + sh[3];
  ss = sh[4] + sh[5] + sh[6] + sh[7];
  float mu  = s * (1.f / NNODES);
  float var = ss * (1.f / NNODES) - mu * mu;
  float rs  = rsqrtf(var + LN_EPS);
  const float4* gv = (const float4*)g;
  const float4* bv = (const float4*)bt;
#pragma unroll
  for (int q = 0; q < 2; ++q) {
    int base = q * 2048 + t * 8;
    float4 g0 = gv[base / 4], g1 = gv[base / 4 + 1];
    float4 b0 = bv[base / 4], b1 = bv[base / 4 + 1];
    short8 sv;
    sv[0] = (short)bf16_rn((f[q][0] - mu) * rs * g0.x + b0.x);
    sv[1] = (short)bf16_rn((f[q][1] - mu) * rs * g0.y + b0.y);
    sv[2] = (short)bf16_rn((f[q][2] - mu) * rs * g0.z + b0.z);
    sv[3] = (short)bf16_rn((f[q][3] - mu) * rs * g0.w + b0.w);
    sv[4] = (short)bf16_rn((f[q][4] - mu) * rs * g1.x + b1.x);
    sv[5] = (short)bf16_rn((f[q][5] - mu) * rs * g1.y + b1.y);
    sv[6] = (short)bf16_rn((f[q][6] - mu) * rs * g1.z + b1.z);
    sv[7] = (short)bf16_rn((f[q][7] - mu) * rs * g1.w + b1.w);
    *(short8*)(out + (size_t)row * NNODES + base) = sv;
  }
}

// ---- 256x256 GEMM: A bf16 (gload_lds), B = f32 W reg-staged+converted in-kernel ----
// 8-phase, BK=64, 2-dbuf LDS. Per-wave VMEM issue order per iter:
//   p0:A2 p1:A2 p2:B4 p3:B4 p4:A2 p5:A2 p6:B4 p7:B4
// waits: p0 vmcnt(6) [Bl(T+1) done] p1 vmcnt(4) [Bh(T+1)] p3 vmcnt(8) [A(T+1) certified]
//        p4 vmcnt(6) [Bl(T+2)] p5 vmcnt(4) [Bh(T+2)] p7 vmcnt(8) [A(T+2) certified]
// B writes: p0/p1 write B(T+1) (loads from prev p6/p7), p4/p5 write B(T+2) (from p2/p3).
// Slot tenancy verified: every LDS overwrite lands >=2 barrier-pairs after the slot's
// last reader phase; writes drain (lgkmcnt(0)) before the phase-closing barrier.

#define VMC(N) asm volatile("s_waitcnt vmcnt(" #N ")" ::: "memory")
#define NOP ((void)0)

#define STAGE_A(T, H)                                                          \
  { load_lds16(Asrc0 + (size_t)((H) * 128) * Kdim + (T) * 64,                  \
               ldsA + ((T) & 1) * 16384 + (H) * 8192 + tid * 8);               \
    load_lds16(Asrc0 + (size_t)((H) * 128 + 64) * Kdim + (T) * 64,             \
               ldsA + ((T) & 1) * 16384 + (H) * 8192 + 4096 + tid * 8); }

#define LOADB(R, T, H)                                                         \
  { const float* p_ = Wp + (size_t)((H) * 128 + bwrow) * Kdim + (T) * 64 + bwc4 * 16; \
    gload4(R[0], p_); gload4(R[1], p_ + 4);                                    \
    gload4(R[2], p_ + 8); gload4(R[3], p_ + 12); }

#define WRITEB(R, T, H)                                                        \
  { u16* d_ = ldsB + ((T) & 1) * 16384 + (H) * 8192 + bwrow * 64;              \
    *(short8*)(d_ + bwg0 * 8) = cvt8(R[0], R[1]);                              \
    *(short8*)(d_ + bwg1 * 8) = cvt8(R[2], R[3]);                              \
    asm volatile("s_waitcnt lgkmcnt(0)" ::: "memory"); }

#define PH(KT, MH, NH, EXTRA, VM_STMT, WR_STMT)                                \
  {                                                                            \
    EXTRA;                                                                     \
    VM_STMT;                                                                   \
    __builtin_amdgcn_sched_barrier(0);                                         \
    WR_STMT;                                                                   \
    __builtin_amdgcn_sched_barrier(0);                                         \
    const u16* Ab = ldsA + ((KT) & 1) * 16384 + aBase + (MH) * 4096;           \
    const u16* Bb = ldsB + ((KT) & 1) * 16384 + bBase + (NH) * 2048;           \
    if ((NH) == 0) {                                                           \
      _Pragma("unroll") for (int mi = 0; mi < 4; ++mi) {                       \
        afr[mi][0] = *(const short8*)(Ab + mi * 1024 + gk0);                   \
        afr[mi][1] = *(const short8*)(Ab + mi * 1024 + gk1);                   \
      }                                                                        \
    }                                                                          \
    if ((MH) == 0) {                                                           \
      _Pragma("unroll") for (int ni = 0; ni < 2; ++ni) {                       \
        bfr[NH][ni][0] = *(const short8*)(Bb + ni * 1024 + gk0);               \
        bfr[NH][ni][1] = *(const short8*)(Bb + ni * 1024 + gk1);               \
      }                                                                        \
    }                                                                          \
    if ((NH) == 0 && (MH) == 0)                                                \
      asm volatile("s_waitcnt lgkmcnt(8)" ::: "memory");                       \
    __builtin_amdgcn_s_barrier();                                              \
    asm volatile("s_waitcnt lgkmcnt(0)" ::: "memory");                         \
    __builtin_amdgcn_sched_barrier(0);                                         \
    __builtin_amdgcn_s_setprio(1);                                             \
    _Pragma("unroll") for (int mi = 0; mi < 4; ++mi)                           \
      _Pragma("unroll") for (int ni = 0; ni < 2; ++ni) {                       \
        acc[(MH) * 4 + mi][(NH) * 2 + ni] =                                    \
          __builtin_amdgcn_mfma_f32_16x16x32_bf16(afr[mi][0], bfr[NH][ni][0],  \
            acc[(MH) * 4 + mi][(NH) * 2 + ni], 0, 0, 0);                       \
        acc[(MH) * 4 + mi][(NH) * 2 + ni] =                                    \
          __builtin_amdgcn_mfma_f32_16x16x32_bf16(afr[mi][1], bfr[NH][ni][1],  \
            acc[(MH) * 4 + mi][(NH) * 2 + ni], 0, 0, 0);                       \
      }                                                                        \
    __builtin_amdgcn_s_setprio(0);                                             \
    __builtin_amdgcn_s_barrier();                                              \
  }

template <bool OUTF32>
__global__ __launch_bounds__(512, 2) void gemm256_kernel(const u16* __restrict__ A,
                                                         const float* __restrict__ W,
                                                         const float* __restrict__ bias,
                                                         const float* __restrict__ slope,
                                                         void* __restrict__ Cv) {
  constexpr int Kdim = NNODES;
  __shared__ u16 lds[65536];           // 128KB: A [0,32768), B [32768,65536)
  u16* ldsA = lds;
  u16* ldsB = lds + 32768;

  const int tid  = threadIdx.x;
  const int lane = tid & 63;
  const int wid  = tid >> 6;
  const int wr   = wid >> 2;
  const int wc   = wid & 3;

  int bid = blockIdx.x;
  int swz = (bid & 7) * 32 + (bid >> 3);
  const int brow = (swz >> 4) * 256;
  const int bcol = (swz & 15) * 256;

  // A staging: thread t -> row t/8, granule (t&7)^(row&7) pre-swizzled source
  const int srow = tid >> 3;
  const int sg   = ((tid & 7) ^ (srow & 7)) * 8;
  const u16* Asrc0 = A + (size_t)(brow + srow) * Kdim + sg;

  // B staging (f32 W): thread t -> row t>>2 (0..127), col-chunk (t&3)*16
  const int bwrow = tid >> 2;
  const int bwc4  = tid & 3;
  const int bwg0  = (2 * bwc4)     ^ (bwrow & 7);
  const int bwg1  = (2 * bwc4 + 1) ^ (bwrow & 7);
  const float* Wp = W + (size_t)bcol * Kdim;

  // ds_read: lane -> row r16, k-quarter kq; granule swizzle key = row&7
  const int r16 = lane & 15, kq = lane >> 4;
  const int g0  = kq ^ (r16 & 7);
  const int gk0 = g0 * 8, gk1 = (g0 ^ 4) * 8;
  const int aBase = wr * 8192 + r16 * 64;
  const int bBase = (wc >> 1) * 8192 + ((wc & 1) * 64 + r16) * 64;

  f32x4 acc[8][4] = {};
  short8 afr[4][2], bfr[2][2][2];
  f32x4 blo[4], bhi[4];

  // prologue: B(0) loads -> write; A(0) staged; B(1) loads left outstanding
  LOADB(blo, 0, 0)
  LOADB(bhi, 0, 1)
  STAGE_A(0, 0)
  STAGE_A(0, 1)
  VMC(4);                              // B(0) done; A(0) outstanding
  __builtin_amdgcn_sched_barrier(0);
  WRITEB(blo, 0, 0)
  WRITEB(bhi, 0, 1)
  LOADB(blo, 1, 0)
  LOADB(bhi, 1, 1)
  VMC(8);                              // A(0) done; B(1) x8 outstanding
  __builtin_amdgcn_s_barrier();

  for (int t = 0; t < 31; ++t) {
    const int T = 2 * t;
    PH(T,     0, 0, STAGE_A(T + 1, 0),   VMC(6), WRITEB(blo, T + 1, 0))
    PH(T,     0, 1, STAGE_A(T + 1, 1),   VMC(4), WRITEB(bhi, T + 1, 1))
    PH(T,     1, 0, LOADB(blo, T + 2, 0), NOP,    NOP)
    PH(T,     1, 1, LOADB(bhi, T + 2, 1), VMC(8), NOP)
    PH(T + 1, 0, 0, STAGE_A(T + 2, 0),   VMC(6), WRITEB(blo, T + 2, 0))
    PH(T + 1, 0, 1, STAGE_A(T + 2, 1),   VMC(4), WRITEB(bhi, T + 2, 1))
    PH(T + 1, 1, 0, LOADB(blo, T + 3, 0), NOP,    NOP)
    PH(T + 1, 1, 1, LOADB(bhi, T + 3, 1), VMC(8), NOP)
  }
  // tail: T=62,63
  PH(62, 0, 0, STAGE_A(63, 0), VMC(6), WRITEB(blo, 63, 0))
  PH(62, 0, 1, STAGE_A(63, 1), VMC(4), WRITEB(bhi, 63, 1))
  PH(62, 1, 0, NOP, NOP, NOP)
  PH(62, 1, 1, NOP, VMC(0), NOP)
  PH(63, 0, 0, NOP, NOP, NOP)
  PH(63, 0, 1, NOP, NOP, NOP)
  PH(63, 1, 0, NOP, NOP, NOP)
  PH(63, 1, 1, NOP, NOP, NOP)

  // epilogue: bias + per-feature LeakyReLU
  const int crow0 = brow + wr * 128 + (lane >> 4) * 4;
  const int ccol0 = bcol + wc * 64 + r16;
#pragma unroll
  for (int n = 0; n < 4; ++n) {
    int col = ccol0 + n * 16;
    float bv = bias[col], sv = slope[col];
#pragma unroll
    for (int m = 0; m < 8; ++m) {
      int row0 = crow0 + m * 16;
#pragma unroll
      for (int r = 0; r < 4; ++r) {
        float vv = acc[m][n][r] + bv;
        vv = vv < 0.f ? vv * sv : vv;
        if constexpr (OUTF32) {
          ((float*)Cv)[(size_t)(row0 + r) * NNODES + col] = vv;
        } else {
          ((u16*)Cv)[(size_t)(row0 + r) * NNODES + col] = bf16_rn(vv);
        }
      }
    }
  }
}

extern "C" void kernel_launch(void* const* d_in, const int* in_sizes, int n_in,
                              void* d_out, int out_size, void* d_ws, size_t ws_size,
                              hipStream_t stream) {
  const float* x     = (const float*)d_in[0];
  const float* ln_g  = (const float*)d_in[1];
  const float* ln_b  = (const float*)d_in[2];
  const float* W     = (const float*)d_in[3];
  const float* b     = (const float*)d_in[4];
  const float* slope = (const float*)d_in[5];
  float* out = (float*)d_out;

  char* ws = (char*)d_ws;
  u16* lnbuf = (u16*)ws;                                   // 32 MB
  u16* ybuf  = (u16*)(ws + (size_t)32 * 1024 * 1024);      // 32 MB (bf16 y)

  const size_t WN = (size_t)NNODES * NNODES;

  for (int i = 0; i < NBLK; ++i) {
    if (i == 0)
      ln_f32_kernel<<<dim3(NBATCH), dim3(256), 0, stream>>>(x, ln_g, ln_b, lnbuf);
    else
      ln_bf16_kernel<<<dim3(NBATCH), dim3(256), 0, stream>>>(ybuf, ln_g + (size_t)i * NNODES,
                                                             ln_b + (size_t)i * NNODES, lnbuf);
    if (i == NBLK - 1)
      gemm256_kernel<true><<<dim3(256), dim3(512), 0, stream>>>(lnbuf, W + WN * i,
                                                                b + (size_t)i * NNODES,
                                                                slope + (size_t)i * NNODES, (void*)out);
    else
      gemm256_kernel<false><<<dim3(256), dim3(512), 0, stream>>>(lnbuf, W + WN * i,
                                                                 b + (size_t)i * NNODES,
                                                                 slope + (size_t)i * NNODES, (void*)ybuf);
  }
}

// Round 9
// 1235.652 us; speedup vs baseline: 1.2752x; 1.2752x over previous
//
#include <hip/hip_runtime.h>
#include <hip/hip_bf16.h>

#define NNODES 4096
#define NBATCH 4096
#define NBLK 8
#define LN_EPS 1e-5f

typedef __attribute__((ext_vector_type(8))) short short8;
typedef __attribute__((ext_vector_type(4))) float f32x4;
typedef __attribute__((ext_vector_type(16))) float f32x16;
typedef __attribute__((ext_vector_type(4))) unsigned short u16x4;
typedef unsigned short u16;

__device__ __forceinline__ u16 bf16_rn(float f) {
  unsigned int u = __builtin_bit_cast(unsigned int, f);
  u += 0x7fffu + ((u >> 16) & 1u);
  return (u16)(u >> 16);
}

__device__ __forceinline__ float bf16_to_f(u16 h) {
  unsigned int u = ((unsigned int)h) << 16;
  return __builtin_bit_cast(float, u);
}

__device__ __forceinline__ void load_lds16(const void* g, void* l) {
  __builtin_amdgcn_global_load_lds((const __attribute__((address_space(1))) void*)g,
                                   (__attribute__((address_space(3))) void*)l,
                                   16, 0, 0);
}

// ---- merged prep: blocks [0,16384) convert W f32->bf16; [16384,16384+4096) LayerNorm ----
template <bool LNF32>
__global__ __launch_bounds__(256) void prep_kernel(const float* __restrict__ W,
                                                   u16* __restrict__ Wb,
                                                   const void* __restrict__ xin,
                                                   const float* __restrict__ g,
                                                   const float* __restrict__ bt,
                                                   u16* __restrict__ lnout) {
  __shared__ float sh[8];
  int t = threadIdx.x;
  if (blockIdx.x < 16384) {
    int idx = blockIdx.x * 256 + t;
    float4 v = ((const float4*)W)[idx];
    u16x4 o;
    o[0] = bf16_rn(v.x); o[1] = bf16_rn(v.y); o[2] = bf16_rn(v.z); o[3] = bf16_rn(v.w);
    ((u16x4*)Wb)[idx] = o;
    return;
  }
  int row = blockIdx.x - 16384;
  float f[16];
  float s = 0.f, ss = 0.f;
  if constexpr (LNF32) {
    const float4* xr = (const float4*)((const float*)xin + (size_t)row * NNODES);
#pragma unroll
    for (int q = 0; q < 4; ++q) {
      float4 v = xr[q * 256 + t];
      f[q * 4 + 0] = v.x; f[q * 4 + 1] = v.y; f[q * 4 + 2] = v.z; f[q * 4 + 3] = v.w;
      s  += v.x + v.y + v.z + v.w;
      ss += v.x * v.x + v.y * v.y + v.z * v.z + v.w * v.w;
    }
  } else {
    const u16* xr = (const u16*)xin + (size_t)row * NNODES;
#pragma unroll
    for (int q = 0; q < 2; ++q) {
      short8 v = *(const short8*)(xr + q * 2048 + t * 8);
#pragma unroll
      for (int j = 0; j < 8; ++j) {
        float fv = bf16_to_f((u16)v[j]);
        f[q * 8 + j] = fv;
        s += fv; ss += fv * fv;
      }
    }
  }
#pragma unroll
  for (int off = 32; off >= 1; off >>= 1) {
    s  += __shfl_xor(s, off, 64);
    ss += __shfl_xor(ss, off, 64);
  }
  int wid = t >> 6, lane = t & 63;
  if (lane == 0) { sh[wid] = s; sh[wid + 4] = ss; }
  __syncthreads();
  s  = sh[0] + sh[1] + sh[2] + sh[3];
  ss = sh[4] + sh[5] + sh[6] + sh[7];
  float mu  = s * (1.f / NNODES);
  float var = ss * (1.f / NNODES) - mu * mu;
  float rs  = rsqrtf(var + LN_EPS);
  if constexpr (LNF32) {
    u16x4* o = (u16x4*)(lnout + (size_t)row * NNODES);
    const float4* gv = (const float4*)g;
    const float4* bv = (const float4*)bt;
#pragma unroll
    for (int q = 0; q < 4; ++q) {
      int i = q * 256 + t;
      float4 gg = gv[i], bb = bv[i];
      u16x4 ov;
      ov[0] = bf16_rn((f[q * 4 + 0] - mu) * rs * gg.x + bb.x);
      ov[1] = bf16_rn((f[q * 4 + 1] - mu) * rs * gg.y + bb.y);
      ov[2] = bf16_rn((f[q * 4 + 2] - mu) * rs * gg.z + bb.z);
      ov[3] = bf16_rn((f[q * 4 + 3] - mu) * rs * gg.w + bb.w);
      o[i] = ov;
    }
  } else {
#pragma unroll
    for (int q = 0; q < 2; ++q) {
      int base = q * 2048 + t * 8;
      float4 g0 = ((const float4*)g)[base / 4], g1 = ((const float4*)g)[base / 4 + 1];
      float4 b0 = ((const float4*)bt)[base / 4], b1 = ((const float4*)bt)[base / 4 + 1];
      short8 sv;
      sv[0] = (short)bf16_rn((f[q * 8 + 0] - mu) * rs * g0.x + b0.x);
      sv[1] = (short)bf16_rn((f[q * 8 + 1] - mu) * rs * g0.y + b0.y);
      sv[2] = (short)bf16_rn((f[q * 8 + 2] - mu) * rs * g0.z + b0.z);
      sv[3] = (short)bf16_rn((f[q * 8 + 3] - mu) * rs * g0.w + b0.w);
      sv[4] = (short)bf16_rn((f[q * 8 + 4] - mu) * rs * g1.x + b1.x);
      sv[5] = (short)bf16_rn((f[q * 8 + 5] - mu) * rs * g1.y + b1.y);
      sv[6] = (short)bf16_rn((f[q * 8 + 6] - mu) * rs * g1.z + b1.z);
      sv[7] = (short)bf16_rn((f[q * 8 + 7] - mu) * rs * g1.w + b1.w);
      *(short8*)(lnout + (size_t)row * NNODES + base) = sv;
    }
  }
}

// ---- 256x256 bf16 NT GEMM, 8 waves, BK=64, 2-dbuf LDS, 8-phase schedule,
//      MFMA 32x32x16 core (round-7 schedule skeleton unchanged) ----
// Phase (KT,MH,NH): reads A m-frags {2MH,2MH+1} when NH==0 (8 ds_read),
// B n-frag NH when MH==0 (4 ds_read); stages 1 half-tile; barrier; lgkmcnt(0);
// 8 x mfma_32x32x16 (2 m-frags x 4 k-steps); barrier.
// Stage map / vmcnt identical to round 7 (proven race-free, absmax-stable).

#define VMC(N) asm volatile("s_waitcnt vmcnt(" #N ")" ::: "memory")

#define STAGE_A(T, H)                                                          \
  { load_lds16(Asrc0 + (size_t)((H) * 128) * Kdim + (T) * 64,                  \
               ldsA + ((T) & 1) * 16384 + (H) * 8192 + tid * 8);               \
    load_lds16(Asrc0 + (size_t)((H) * 128 + 64) * Kdim + (T) * 64,             \
               ldsA + ((T) & 1) * 16384 + (H) * 8192 + 4096 + tid * 8); }

#define STAGE_B(T, H)                                                          \
  { load_lds16(Bsrc0 + (size_t)((H) * 128) * Kdim + (T) * 64,                  \
               ldsB + ((T) & 1) * 16384 + (H) * 8192 + tid * 8);               \
    load_lds16(Bsrc0 + (size_t)((H) * 128 + 64) * Kdim + (T) * 64,             \
               ldsB + ((T) & 1) * 16384 + (H) * 8192 + 4096 + tid * 8); }

#define PH(KT, MH, NH, STAGE_STMT, VM_STMT)                                    \
  {                                                                            \
    const u16* Ab = ldsA + ((KT) & 1) * 16384 + aBase + (MH) * 4096;           \
    const u16* Bb = ldsB + ((KT) & 1) * 16384 + bBase + (NH) * 2048;           \
    if ((NH) == 0) {                                                           \
      _Pragma("unroll") for (int mi = 0; mi < 2; ++mi)                         \
        _Pragma("unroll") for (int ks = 0; ks < 4; ++ks)                       \
          afr[mi][ks] = *(const short8*)(Ab + mi * 2048 + gks[ks]);            \
    }                                                                          \
    if ((MH) == 0) {                                                           \
      _Pragma("unroll") for (int ks = 0; ks < 4; ++ks)                         \
        bfr[NH][ks] = *(const short8*)(Bb + gks[ks]);                          \
    }                                                                          \
    STAGE_STMT;                                                                \
    if ((NH) == 0 && (MH) == 0)                                                \
      asm volatile("s_waitcnt lgkmcnt(8)" ::: "memory");                       \
    VM_STMT;                                                                   \
    __builtin_amdgcn_s_barrier();                                              \
    asm volatile("s_waitcnt lgkmcnt(0)" ::: "memory");                         \
    __builtin_amdgcn_sched_barrier(0);                                         \
    __builtin_amdgcn_s_setprio(1);                                             \
    _Pragma("unroll") for (int mi = 0; mi < 2; ++mi)                           \
      _Pragma("unroll") for (int ks = 0; ks < 4; ++ks)                         \
        acc[(MH) * 2 + mi][NH] =                                               \
          __builtin_amdgcn_mfma_f32_32x32x16_bf16(afr[mi][ks], bfr[NH][ks],    \
            acc[(MH) * 2 + mi][NH], 0, 0, 0);                                  \
    __builtin_amdgcn_s_setprio(0);                                             \
    __builtin_amdgcn_s_barrier();                                              \
  }

template <bool OUTF32>
__global__ __launch_bounds__(512, 2) void gemm256_kernel(const u16* __restrict__ A,
                                                         const u16* __restrict__ B,
                                                         const float* __restrict__ bias,
                                                         const float* __restrict__ slope,
                                                         void* __restrict__ Cv) {
  constexpr int Kdim = NNODES;
  __shared__ u16 lds[65536];           // 128KB: A [0,32768), B [32768,65536)
  u16* ldsA = lds;
  u16* ldsB = lds + 32768;

  const int tid  = threadIdx.x;
  const int lane = tid & 63;
  const int wid  = tid >> 6;
  const int wr   = wid >> 2;           // 0..1 : 128-row half
  const int wc   = wid & 3;            // 0..3 : 64-col quarter

  // XCD-aware bijective swizzle (256 blocks, 8 XCDs)
  int bid = blockIdx.x;
  int swz = (bid & 7) * 32 + (bid >> 3);
  const int brow = (swz >> 4) * 256;
  const int bcol = (swz & 15) * 256;

  // staging source: thread t -> row t/8, granule (t&7) XOR (row&7)  (pre-swizzled)
  const int srow = tid >> 3;
  const int sg   = ((tid & 7) ^ (srow & 7)) * 8;
  const u16* Asrc0 = A + (size_t)(brow + srow) * Kdim + sg;
  const u16* Bsrc0 = B + (size_t)(bcol + srow) * Kdim + sg;

  // ds_read (32x32x16 frags): lane -> row r32 = lane&31, k-half kh = lane>>5;
  // global k-granule for k-step ks is (ks*2+kh); LDS granule = that ^ (r32&7)
  const int r32 = lane & 31;
  const int kh  = lane >> 5;
  const int rk  = r32 & 7;
  int gks[4];
#pragma unroll
  for (int ks = 0; ks < 4; ++ks) gks[ks] = ((ks * 2 + kh) ^ rk) * 8;
  const int aBase = wr * 8192 + r32 * 64;   // + mf*2048 per m-frag
  const int bBase = wc * 4096 + r32 * 64;   // + nf*2048 per n-frag

  f32x16 acc[4][2] = {};
  short8 afr[2][4], bfr[2][4];

  // prologue: stage B(0), A(0), B(1) halves (12 loads, steady-state order);
  // vmcnt(4) certifies tile 0 (leaves B-lo(1),B-hi(1) outstanding)
  STAGE_B(0, 0) STAGE_B(0, 1) STAGE_A(0, 0) STAGE_A(0, 1) STAGE_B(1, 0) STAGE_B(1, 1)
  VMC(4);
  __builtin_amdgcn_s_barrier();

  for (int t = 0; t < 31; ++t) {
    const int T = 2 * t;
    PH(T,     0, 0, STAGE_A(T + 1, 0), ;)
    PH(T,     0, 1, STAGE_A(T + 1, 1), ;)
    PH(T,     1, 0, STAGE_B(T + 2, 0), ;)
    PH(T,     1, 1, STAGE_B(T + 2, 1), VMC(4))
    PH(T + 1, 0, 0, STAGE_A(T + 2, 0), ;)
    PH(T + 1, 0, 1, STAGE_A(T + 2, 1), ;)
    PH(T + 1, 1, 0, STAGE_B(T + 3, 0), ;)
    PH(T + 1, 1, 1, STAGE_B(T + 3, 1), VMC(4))
  }
  // tail: T = 62 (stage only A(63); vmcnt(0) certifies tile 63)
  PH(62, 0, 0, STAGE_A(63, 0), ;)
  PH(62, 0, 1, STAGE_A(63, 1), ;)
  PH(62, 1, 0, ;, ;)
  PH(62, 1, 1, ;, VMC(0))
  PH(63, 0, 0, ;, ;)
  PH(63, 0, 1, ;, ;)
  PH(63, 1, 0, ;, ;)
  PH(63, 1, 1, ;, ;)

  // epilogue: bias + per-feature LeakyReLU; 32x32 D-layout:
  // col = lane&31, row = (reg&3) + 8*(reg>>2) + 4*(lane>>5)
  const int rowoff = 4 * kh;
#pragma unroll
  for (int nf = 0; nf < 2; ++nf) {
    int col = bcol + wc * 64 + nf * 32 + r32;
    float bv = bias[col], sv = slope[col];
#pragma unroll
    for (int mf = 0; mf < 4; ++mf) {
      int row_base = brow + wr * 128 + mf * 32 + rowoff;
#pragma unroll
      for (int r = 0; r < 16; ++r) {
        int row = row_base + (r & 3) + 8 * (r >> 2);
        float vv = acc[mf][nf][r] + bv;
        vv = vv < 0.f ? vv * sv : vv;
        if constexpr (OUTF32) {
          ((float*)Cv)[(size_t)row * NNODES + col] = vv;
        } else {
          ((u16*)Cv)[(size_t)row * NNODES + col] = bf16_rn(vv);
        }
      }
    }
  }
}

extern "C" void kernel_launch(void* const* d_in, const int* in_sizes, int n_in,
                              void* d_out, int out_size, void* d_ws, size_t ws_size,
                              hipStream_t stream) {
  const float* x     = (const float*)d_in[0];
  const float* ln_g  = (const float*)d_in[1];
  const float* ln_b  = (const float*)d_in[2];
  const float* W     = (const float*)d_in[3];
  const float* b     = (const float*)d_in[4];
  const float* slope = (const float*)d_in[5];
  float* out = (float*)d_out;

  char* ws = (char*)d_ws;
  u16* Wbuf  = (u16*)ws;                                   // 32 MB
  u16* lnbuf = (u16*)(ws + (size_t)32 * 1024 * 1024);      // 32 MB
  u16* ybuf  = (u16*)(ws + (size_t)64 * 1024 * 1024);      // 32 MB (bf16 y)

  const size_t WN = (size_t)NNODES * NNODES;
  const dim3 pgrid(16384 + NBATCH);

  for (int i = 0; i < NBLK; ++i) {
    if (i == 0)
      prep_kernel<true><<<pgrid, dim3(256), 0, stream>>>(W, Wbuf, (const void*)x,
                                                         ln_g, ln_b, lnbuf);
    else
      prep_kernel<false><<<pgrid, dim3(256), 0, stream>>>(W + WN * i, Wbuf, (const void*)ybuf,
                                                          ln_g + (size_t)i * NNODES,
                                                          ln_b + (size_t)i * NNODES, lnbuf);
    if (i == NBLK - 1)
      gemm256_kernel<true><<<dim3(256), dim3(512), 0, stream>>>(lnbuf, Wbuf,
                                                                b + (size_t)i * NNODES,
                                                                slope + (size_t)i * NNODES, (void*)out);
    else
      gemm256_kernel<false><<<dim3(256), dim3(512), 0, stream>>>(lnbuf, Wbuf,
                                                                 b + (size_t)i * NNODES,
                                                                 slope + (size_t)i * NNODES, (void*)ybuf);
  }
}

// Round 10
// 1094.959 us; speedup vs baseline: 1.4390x; 1.1285x over previous
//
#include <hip/hip_runtime.h>
#include <hip/hip_bf16.h>

#define NNODES 4096
#define NBATCH 4096
#define NBLK 8
#define LN_EPS 1e-5f

typedef __attribute__((ext_vector_type(8))) short short8;
typedef __attribute__((ext_vector_type(4))) float f32x4;
typedef __attribute__((ext_vector_type(4))) unsigned short u16x4;
typedef unsigned short u16;

__device__ __forceinline__ u16 bf16_rn(float f) {
  unsigned int u = __builtin_bit_cast(unsigned int, f);
  u += 0x7fffu + ((u >> 16) & 1u);
  return (u16)(u >> 16);
}

__device__ __forceinline__ float bf16_to_f(u16 h) {
  unsigned int u = ((unsigned int)h) << 16;
  return __builtin_bit_cast(float, u);
}

__device__ __forceinline__ void load_lds16(const void* g, void* l) {
  __builtin_amdgcn_global_load_lds((const __attribute__((address_space(1))) void*)g,
                                   (__attribute__((address_space(3))) void*)l,
                                   16, 0, 0);
}

// ---- merged prep for layer 0: blocks [0,16384) convert W0; [16384,20480) LN(x f32) ----
template <bool LNF32>
__global__ __launch_bounds__(256) void prep_kernel(const float* __restrict__ W,
                                                   u16* __restrict__ Wb,
                                                   const void* __restrict__ xin,
                                                   const float* __restrict__ g,
                                                   const float* __restrict__ bt,
                                                   u16* __restrict__ lnout) {
  __shared__ float sh[8];
  int t = threadIdx.x;
  if (blockIdx.x < 16384) {
    int idx = blockIdx.x * 256 + t;
    float4 v = ((const float4*)W)[idx];
    u16x4 o;
    o[0] = bf16_rn(v.x); o[1] = bf16_rn(v.y); o[2] = bf16_rn(v.z); o[3] = bf16_rn(v.w);
    ((u16x4*)Wb)[idx] = o;
    return;
  }
  int row = blockIdx.x - 16384;
  float f[16];
  float s = 0.f, ss = 0.f;
  const float4* xr = (const float4*)((const float*)xin + (size_t)row * NNODES);
#pragma unroll
  for (int q = 0; q < 4; ++q) {
    float4 v = xr[q * 256 + t];
    f[q * 4 + 0] = v.x; f[q * 4 + 1] = v.y; f[q * 4 + 2] = v.z; f[q * 4 + 3] = v.w;
    s  += v.x + v.y + v.z + v.w;
    ss += v.x * v.x + v.y * v.y + v.z * v.z + v.w * v.w;
  }
#pragma unroll
  for (int off = 32; off >= 1; off >>= 1) {
    s  += __shfl_xor(s, off, 64);
    ss += __shfl_xor(ss, off, 64);
  }
  int wid = t >> 6, lane = t & 63;
  if (lane == 0) { sh[wid] = s; sh[wid + 4] = ss; }
  __syncthreads();
  s  = sh[0] + sh[1] + sh[2] + sh[3];
  ss = sh[4] + sh[5] + sh[6] + sh[7];
  float mu  = s * (1.f / NNODES);
  float var = ss * (1.f / NNODES) - mu * mu;
  float rs  = rsqrtf(var + LN_EPS);
  u16x4* o = (u16x4*)(lnout + (size_t)row * NNODES);
  const float4* gv = (const float4*)g;
  const float4* bv = (const float4*)bt;
#pragma unroll
  for (int q = 0; q < 4; ++q) {
    int i = q * 256 + t;
    float4 gg = gv[i], bb = bv[i];
    u16x4 ov;
    ov[0] = bf16_rn((f[q * 4 + 0] - mu) * rs * gg.x + bb.x);
    ov[1] = bf16_rn((f[q * 4 + 1] - mu) * rs * gg.y + bb.y);
    ov[2] = bf16_rn((f[q * 4 + 2] - mu) * rs * gg.z + bb.z);
    ov[3] = bf16_rn((f[q * 4 + 3] - mu) * rs * gg.w + bb.w);
    o[i] = ov;
  }
}

// ---- row LayerNorm, bf16 input (layers 1..7) -> bf16 out ----
__global__ __launch_bounds__(256) void ln_bf16_kernel(const u16* __restrict__ x,
                                                      const float* __restrict__ g,
                                                      const float* __restrict__ bt,
                                                      u16* __restrict__ out) {
  int row = blockIdx.x;
  int t = threadIdx.x;
  const u16* xr = x + (size_t)row * NNODES;
  float f[2][8];
  float s = 0.f, ss = 0.f;
#pragma unroll
  for (int q = 0; q < 2; ++q) {
    short8 v = *(const short8*)(xr + q * 2048 + t * 8);
#pragma unroll
    for (int j = 0; j < 8; ++j) {
      float fv = bf16_to_f((u16)v[j]);
      f[q][j] = fv;
      s += fv; ss += fv * fv;
    }
  }
#pragma unroll
  for (int off = 32; off >= 1; off >>= 1) {
    s  += __shfl_xor(s, off, 64);
    ss += __shfl_xor(ss, off, 64);
  }
  __shared__ float sh[8];
  int wid = t >> 6, lane = t & 63;
  if (lane == 0) { sh[wid] = s; sh[wid + 4] = ss; }
  __syncthreads();
  s  = sh[0] + sh[1] + sh[2] + sh[3];
  ss = sh[4] + sh[5] + sh[6] + sh[7];
  float mu  = s * (1.f / NNODES);
  float var = ss * (1.f / NNODES) - mu * mu;
  float rs  = rsqrtf(var + LN_EPS);
  const float4* gv = (const float4*)g;
  const float4* bv = (const float4*)bt;
#pragma unroll
  for (int q = 0; q < 2; ++q) {
    int base = q * 2048 + t * 8;
    float4 g0 = gv[base / 4], g1 = gv[base / 4 + 1];
    float4 b0 = bv[base / 4], b1 = bv[base / 4 + 1];
    short8 sv;
    sv[0] = (short)bf16_rn((f[q][0] - mu) * rs * g0.x + b0.x);
    sv[1] = (short)bf16_rn((f[q][1] - mu) * rs * g0.y + b0.y);
    sv[2] = (short)bf16_rn((f[q][2] - mu) * rs * g0.z + b0.z);
    sv[3] = (short)bf16_rn((f[q][3] - mu) * rs * g0.w + b0.w);
    sv[4] = (short)bf16_rn((f[q][4] - mu) * rs * g1.x + b1.x);
    sv[5] = (short)bf16_rn((f[q][5] - mu) * rs * g1.y + b1.y);
    sv[6] = (short)bf16_rn((f[q][6] - mu) * rs * g1.z + b1.z);
    sv[7] = (short)bf16_rn((f[q][7] - mu) * rs * g1.w + b1.w);
    *(short8*)(out + (size_t)row * NNODES + base) = sv;
  }
}

// ---- 256x256 bf16 NT GEMM, round-7 8-phase schedule + injected W(i+1) convert ----
// Conv chunks (t<16, 2/iter): raw-asm load before VMC(4) (lands in newest-4 window,
// certification only strengthens); cvt+store after VMC(4)+sched_barrier(0) (rule #18);
// load->store spans 4 phases, drained by the intervening VMC(4); store retires by the
// next VMC(4) (older than its newest-4). Counts otherwise identical to round 7.

#define VMC(N) asm volatile("s_waitcnt vmcnt(" #N ")" ::: "memory")

#define STAGE_A(T, H)                                                          \
  { load_lds16(Asrc0 + (size_t)((H) * 128) * Kdim + (T) * 64,                  \
               ldsA + ((T) & 1) * 16384 + (H) * 8192 + tid * 8);               \
    load_lds16(Asrc0 + (size_t)((H) * 128 + 64) * Kdim + (T) * 64,             \
               ldsA + ((T) & 1) * 16384 + (H) * 8192 + 4096 + tid * 8); }

#define STAGE_B(T, H)                                                          \
  { load_lds16(Bsrc0 + (size_t)((H) * 128) * Kdim + (T) * 64,                  \
               ldsB + ((T) & 1) * 16384 + (H) * 8192 + tid * 8);               \
    load_lds16(Bsrc0 + (size_t)((H) * 128 + 64) * Kdim + (T) * 64,             \
               ldsB + ((T) & 1) * 16384 + (H) * 8192 + 4096 + tid * 8); }

#define CVSTORE(SRC, CIDX)                                                     \
  { __builtin_amdgcn_sched_barrier(0);                                         \
    u16x4 o_;                                                                  \
    o_[0] = bf16_rn(SRC[0]); o_[1] = bf16_rn(SRC[1]);                          \
    o_[2] = bf16_rn(SRC[2]); o_[3] = bf16_rn(SRC[3]);                          \
    *(u16x4*)(Wnd + cvoff + (size_t)(CIDX) * 2048) = o_; }

#define CONVP3                                                                 \
  { if (CONVON && t < 16) {                                                    \
      const float* cp_ = Wns + cvoff + (size_t)(2 * t) * 2048;                 \
      asm volatile("global_load_dwordx4 %0, %1, off"                           \
                   : "=&v"(cvA) : "v"(cp_) : "memory");                        \
    }                                                                          \
    VMC(4);                                                                    \
    if (CONVON && t >= 1 && t <= 16) CVSTORE(cvB, 2 * t - 1) }

#define CONVP7                                                                 \
  { if (CONVON && t < 16) {                                                    \
      const float* cp_ = Wns + cvoff + (size_t)(2 * t + 1) * 2048;             \
      asm volatile("global_load_dwordx4 %0, %1, off"                           \
                   : "=&v"(cvB) : "v"(cp_) : "memory");                        \
    }                                                                          \
    VMC(4);                                                                    \
    if (CONVON && t < 16) CVSTORE(cvA, 2 * t) }

#define PH(KT, MH, NH, STAGE_STMT, VM_STMT)                                    \
  {                                                                            \
    const u16* Ab = ldsA + ((KT) & 1) * 16384 + aBase + (MH) * 4096;           \
    const u16* Bb = ldsB + ((KT) & 1) * 16384 + bBase + (NH) * 2048;           \
    if ((NH) == 0) {                                                           \
      _Pragma("unroll") for (int mi = 0; mi < 4; ++mi) {                       \
        afr[mi][0] = *(const short8*)(Ab + mi * 1024 + gk0);                   \
        afr[mi][1] = *(const short8*)(Ab + mi * 1024 + gk1);                   \
      }                                                                        \
    }                                                                          \
    if ((MH) == 0) {                                                           \
      _Pragma("unroll") for (int ni = 0; ni < 2; ++ni) {                       \
        bfr[NH][ni][0] = *(const short8*)(Bb + ni * 1024 + gk0);               \
        bfr[NH][ni][1] = *(const short8*)(Bb + ni * 1024 + gk1);               \
      }                                                                        \
    }                                                                          \
    STAGE_STMT;                                                                \
    if ((NH) == 0 && (MH) == 0)                                                \
      asm volatile("s_waitcnt lgkmcnt(8)" ::: "memory");                       \
    VM_STMT;                                                                   \
    __builtin_amdgcn_s_barrier();                                              \
    asm volatile("s_waitcnt lgkmcnt(0)" ::: "memory");                         \
    __builtin_amdgcn_sched_barrier(0);                                         \
    __builtin_amdgcn_s_setprio(1);                                             \
    _Pragma("unroll") for (int mi = 0; mi < 4; ++mi)                           \
      _Pragma("unroll") for (int ni = 0; ni < 2; ++ni) {                       \
        acc[(MH) * 4 + mi][(NH) * 2 + ni] =                                    \
          __builtin_amdgcn_mfma_f32_16x16x32_bf16(afr[mi][0], bfr[NH][ni][0],  \
            acc[(MH) * 4 + mi][(NH) * 2 + ni], 0, 0, 0);                       \
        acc[(MH) * 4 + mi][(NH) * 2 + ni] =                                    \
          __builtin_amdgcn_mfma_f32_16x16x32_bf16(afr[mi][1], bfr[NH][ni][1],  \
            acc[(MH) * 4 + mi][(NH) * 2 + ni], 0, 0, 0);                       \
      }                                                                        \
    __builtin_amdgcn_s_setprio(0);                                             \
    __builtin_amdgcn_s_barrier();                                              \
  }

template <bool OUTF32, bool CONVON>
__global__ __launch_bounds__(512, 2) void gemm256_kernel(const u16* __restrict__ A,
                                                         const u16* __restrict__ B,
                                                         const float* __restrict__ bias,
                                                         const float* __restrict__ slope,
                                                         void* __restrict__ Cv,
                                                         const float* __restrict__ Wns,
                                                         u16* __restrict__ Wnd) {
  constexpr int Kdim = NNODES;
  __shared__ u16 lds[65536];           // 128KB: A [0,32768), B [32768,65536)
  u16* ldsA = lds;
  u16* ldsB = lds + 32768;

  const int tid  = threadIdx.x;
  const int lane = tid & 63;
  const int wid  = tid >> 6;
  const int wr   = wid >> 2;           // 0..1 : 128-row half
  const int wc   = wid & 3;            // 0..3 : 64-col quarter

  // XCD-aware bijective swizzle (256 blocks, 8 XCDs)
  int bid = blockIdx.x;
  int swz = (bid & 7) * 32 + (bid >> 3);
  const int brow = (swz >> 4) * 256;
  const int bcol = (swz & 15) * 256;

  // staging source: thread t -> row t/8, granule (t&7) XOR (row&7)  (pre-swizzled)
  const int srow = tid >> 3;
  const int sg   = ((tid & 7) ^ (srow & 7)) * 8;
  const u16* Asrc0 = A + (size_t)(brow + srow) * Kdim + sg;
  const u16* Bsrc0 = B + (size_t)(bcol + srow) * Kdim + sg;

  // ds_read: lane -> row r16, k-quarter kq; granule g = (ks*4+kq) ^ (r16&7)
  const int r16 = lane & 15, kq = lane >> 4;
  const int g0  = kq ^ (r16 & 7);
  const int gk0 = g0 * 8, gk1 = (g0 ^ 4) * 8;
  const int aBase = wr * 8192 + r16 * 64;
  const int bBase = (wc >> 1) * 8192 + ((wc & 1) * 64 + r16) * 64;

  // W(i+1) conversion: block bid converts 64K f32 (32 chunks x 512thr x float4)
  const size_t cvoff = (size_t)bid * 65536 + tid * 4;
  f32x4 cvA, cvB;

  f32x4 acc[8][4] = {};
  short8 afr[4][2], bfr[2][2][2];

  // prologue: stage B(0), A(0), B(1) halves (12 loads, steady-state order);
  // vmcnt(4) certifies tile 0 (leaves B-lo(1),B-hi(1) outstanding)
  STAGE_B(0, 0) STAGE_B(0, 1) STAGE_A(0, 0) STAGE_A(0, 1) STAGE_B(1, 0) STAGE_B(1, 1)
  VMC(4);
  __builtin_amdgcn_s_barrier();

  for (int t = 0; t < 31; ++t) {
    const int T = 2 * t;
    PH(T,     0, 0, STAGE_A(T + 1, 0), ;)
    PH(T,     0, 1, STAGE_A(T + 1, 1), ;)
    PH(T,     1, 0, STAGE_B(T + 2, 0), ;)
    PH(T,     1, 1, STAGE_B(T + 2, 1), CONVP3)
    PH(T + 1, 0, 0, STAGE_A(T + 2, 0), ;)
    PH(T + 1, 0, 1, STAGE_A(T + 2, 1), ;)
    PH(T + 1, 1, 0, STAGE_B(T + 3, 0), ;)
    PH(T + 1, 1, 1, STAGE_B(T + 3, 1), CONVP7)
  }
  // tail: T = 62 (stage only A(63); vmcnt(0) certifies tile 63)
  PH(62, 0, 0, STAGE_A(63, 0), ;)
  PH(62, 0, 1, STAGE_A(63, 1), ;)
  PH(62, 1, 0, ;, ;)
  PH(62, 1, 1, ;, VMC(0))
  PH(63, 0, 0, ;, ;)
  PH(63, 0, 1, ;, ;)
  PH(63, 1, 0, ;, ;)
  PH(63, 1, 1, ;, ;)

  // epilogue: bias + per-feature LeakyReLU
  const int crow0 = brow + wr * 128 + (lane >> 4) * 4;
  const int ccol0 = bcol + wc * 64 + r16;
#pragma unroll
  for (int n = 0; n < 4; ++n) {
    int col = ccol0 + n * 16;
    float bv = bias[col], sv = slope[col];
#pragma unroll
    for (int m = 0; m < 8; ++m) {
      int row0 = crow0 + m * 16;
#pragma unroll
      for (int r = 0; r < 4; ++r) {
        float vv = acc[m][n][r] + bv;
        vv = vv < 0.f ? vv * sv : vv;
        if constexpr (OUTF32) {
          ((float*)Cv)[(size_t)(row0 + r) * NNODES + col] = vv;
        } else {
          ((u16*)Cv)[(size_t)(row0 + r) * NNODES + col] = bf16_rn(vv);
        }
      }
    }
  }
}

extern "C" void kernel_launch(void* const* d_in, const int* in_sizes, int n_in,
                              void* d_out, int out_size, void* d_ws, size_t ws_size,
                              hipStream_t stream) {
  const float* x     = (const float*)d_in[0];
  const float* ln_g  = (const float*)d_in[1];
  const float* ln_b  = (const float*)d_in[2];
  const float* W     = (const float*)d_in[3];
  const float* b     = (const float*)d_in[4];
  const float* slope = (const float*)d_in[5];
  float* out = (float*)d_out;

  char* ws = (char*)d_ws;
  u16* Wbuf0 = (u16*)ws;                                   // 32 MB
  u16* Wbuf1 = (u16*)(ws + (size_t)32 * 1024 * 1024);      // 32 MB
  u16* lnbuf = (u16*)(ws + (size_t)64 * 1024 * 1024);      // 32 MB
  u16* ybuf  = (u16*)(ws + (size_t)96 * 1024 * 1024);      // 32 MB (bf16 y)

  const size_t WN = (size_t)NNODES * NNODES;

  for (int i = 0; i < NBLK; ++i) {
    u16* Wc = (i & 1) ? Wbuf1 : Wbuf0;
    u16* Wn = (i & 1) ? Wbuf0 : Wbuf1;
    if (i == 0)
      prep_kernel<true><<<dim3(16384 + NBATCH), dim3(256), 0, stream>>>(
          W, Wbuf0, (const void*)x, ln_g, ln_b, lnbuf);
    else
      ln_bf16_kernel<<<dim3(NBATCH), dim3(256), 0, stream>>>(
          ybuf, ln_g + (size_t)i * NNODES, ln_b + (size_t)i * NNODES, lnbuf);

    if (i == NBLK - 1)
      gemm256_kernel<true, false><<<dim3(256), dim3(512), 0, stream>>>(
          lnbuf, Wc, b + (size_t)i * NNODES, slope + (size_t)i * NNODES,
          (void*)out, nullptr, nullptr);
    else
      gemm256_kernel<false, true><<<dim3(256), dim3(512), 0, stream>>>(
          lnbuf, Wc, b + (size_t)i * NNODES, slope + (size_t)i * NNODES,
          (void*)ybuf, W + WN * (i + 1), Wn);
  }
}

// Round 11
// 1052.261 us; speedup vs baseline: 1.4974x; 1.0406x over previous
//
#include <hip/hip_runtime.h>
#include <hip/hip_bf16.h>

#define NNODES 4096
#define NBATCH 4096
#define NBLK 8
#define LN_EPS 1e-5f

typedef __attribute__((ext_vector_type(8))) short short8;
typedef __attribute__((ext_vector_type(4))) float f32x4;
typedef __attribute__((ext_vector_type(4))) unsigned short u16x4;
typedef unsigned short u16;

__device__ __forceinline__ u16 bf16_rn(float f) {
  unsigned int u = __builtin_bit_cast(unsigned int, f);
  u += 0x7fffu + ((u >> 16) & 1u);
  return (u16)(u >> 16);
}

__device__ __forceinline__ float bf16_to_f(u16 h) {
  unsigned int u = ((unsigned int)h) << 16;
  return __builtin_bit_cast(float, u);
}

__device__ __forceinline__ void load_lds16(const void* g, void* l) {
  __builtin_amdgcn_global_load_lds((const __attribute__((address_space(1))) void*)g,
                                   (__attribute__((address_space(3))) void*)l,
                                   16, 0, 0);
}

// ---- merged prep for layer 0: blocks [0,16384) convert W0; [16384,20480) LN(x f32) ----
__global__ __launch_bounds__(256) void prep_kernel(const float* __restrict__ W,
                                                   u16* __restrict__ Wb,
                                                   const float* __restrict__ xin,
                                                   const float* __restrict__ g,
                                                   const float* __restrict__ bt,
                                                   u16* __restrict__ lnout) {
  __shared__ float sh[8];
  int t = threadIdx.x;
  if (blockIdx.x < 16384) {
    int idx = blockIdx.x * 256 + t;
    float4 v = ((const float4*)W)[idx];
    u16x4 o;
    o[0] = bf16_rn(v.x); o[1] = bf16_rn(v.y); o[2] = bf16_rn(v.z); o[3] = bf16_rn(v.w);
    ((u16x4*)Wb)[idx] = o;
    return;
  }
  int row = blockIdx.x - 16384;
  float f[16];
  float s = 0.f, ss = 0.f;
  const float4* xr = (const float4*)(xin + (size_t)row * NNODES);
#pragma unroll
  for (int q = 0; q < 4; ++q) {
    float4 v = xr[q * 256 + t];
    f[q * 4 + 0] = v.x; f[q * 4 + 1] = v.y; f[q * 4 + 2] = v.z; f[q * 4 + 3] = v.w;
    s  += v.x + v.y + v.z + v.w;
    ss += v.x * v.x + v.y * v.y + v.z * v.z + v.w * v.w;
  }
#pragma unroll
  for (int off = 32; off >= 1; off >>= 1) {
    s  += __shfl_xor(s, off, 64);
    ss += __shfl_xor(ss, off, 64);
  }
  int wid = t >> 6, lane = t & 63;
  if (lane == 0) { sh[wid] = s; sh[wid + 4] = ss; }
  __syncthreads();
  s  = sh[0] + sh[1] + sh[2] + sh[3];
  ss = sh[4] + sh[5] + sh[6] + sh[7];
  float mu  = s * (1.f / NNODES);
  float var = ss * (1.f / NNODES) - mu * mu;
  float rs  = rsqrtf(var + LN_EPS);
  u16x4* o = (u16x4*)(lnout + (size_t)row * NNODES);
  const float4* gv = (const float4*)g;
  const float4* bv = (const float4*)bt;
#pragma unroll
  for (int q = 0; q < 4; ++q) {
    int i = q * 256 + t;
    float4 gg = gv[i], bb = bv[i];
    u16x4 ov;
    ov[0] = bf16_rn((f[q * 4 + 0] - mu) * rs * gg.x + bb.x);
    ov[1] = bf16_rn((f[q * 4 + 1] - mu) * rs * gg.y + bb.y);
    ov[2] = bf16_rn((f[q * 4 + 2] - mu) * rs * gg.z + bb.z);
    ov[3] = bf16_rn((f[q * 4 + 3] - mu) * rs * gg.w + bb.w);
    o[i] = ov;
  }
}

// ---- row LayerNorm, bf16 input (layers 1..7) -> bf16 out ----
__global__ __launch_bounds__(256) void ln_bf16_kernel(const u16* __restrict__ x,
                                                      const float* __restrict__ g,
                                                      const float* __restrict__ bt,
                                                      u16* __restrict__ out) {
  int row = blockIdx.x;
  int t = threadIdx.x;
  const u16* xr = x + (size_t)row * NNODES;
  float f[2][8];
  float s = 0.f, ss = 0.f;
#pragma unroll
  for (int q = 0; q < 2; ++q) {
    short8 v = *(const short8*)(xr + q * 2048 + t * 8);
#pragma unroll
    for (int j = 0; j < 8; ++j) {
      float fv = bf16_to_f((u16)v[j]);
      f[q][j] = fv;
      s += fv; ss += fv * fv;
    }
  }
#pragma unroll
  for (int off = 32; off >= 1; off >>= 1) {
    s  += __shfl_xor(s, off, 64);
    ss += __shfl_xor(ss, off, 64);
  }
  __shared__ float sh[8];
  int wid = t >> 6, lane = t & 63;
  if (lane == 0) { sh[wid] = s; sh[wid + 4] = ss; }
  __syncthreads();
  s  = sh[0] + sh[1] + sh[2] + sh[3];
  ss = sh[4] + sh[5] + sh[6] + sh[7];
  float mu  = s * (1.f / NNODES);
  float var = ss * (1.f / NNODES) - mu * mu;
  float rs  = rsqrtf(var + LN_EPS);
  const float4* gv = (const float4*)g;
  const float4* bv = (const float4*)bt;
#pragma unroll
  for (int q = 0; q < 2; ++q) {
    int base = q * 2048 + t * 8;
    float4 g0 = gv[base / 4], g1 = gv[base / 4 + 1];
    float4 b0 = bv[base / 4], b1 = bv[base / 4 + 1];
    short8 sv;
    sv[0] = (short)bf16_rn((f[q][0] - mu) * rs * g0.x + b0.x);
    sv[1] = (short)bf16_rn((f[q][1] - mu) * rs * g0.y + b0.y);
    sv[2] = (short)bf16_rn((f[q][2] - mu) * rs * g0.z + b0.z);
    sv[3] = (short)bf16_rn((f[q][3] - mu) * rs * g0.w + b0.w);
    sv[4] = (short)bf16_rn((f[q][4] - mu) * rs * g1.x + b1.x);
    sv[5] = (short)bf16_rn((f[q][5] - mu) * rs * g1.y + b1.y);
    sv[6] = (short)bf16_rn((f[q][6] - mu) * rs * g1.z + b1.z);
    sv[7] = (short)bf16_rn((f[q][7] - mu) * rs * g1.w + b1.w);
    *(short8*)(out + (size_t)row * NNODES + base) = sv;
  }
}

// ---- 256x256 bf16 NT GEMM, 8 waves, BK=64, 2-dbuf, 8-phase, SINGLE barrier/phase ----
// Layout per phase: [reads][stage][VMC?][BARRIER][lgkm0][MFMA]. Passing BARRIER_p
// certifies all waves executed lgkm0/MFMA of p-1 => all reads <= p-1 drained.
// Stage map (shifted so every overwrite is >=2 phases after its buffer's last reader):
//   p0:A(T+1,0) p1:A(T+1,1) p2:conv-only p3:B(T+2,0) p4:B(T+2,1)
//   p5:A(T+2,0) p6:A(T+2,1) p7:B(T+3,0)+B(T+3,1)
// Certs: tile T+1 @p3 (newer = p3 stage 2 [+conv 4 -> 6; t in {0,16} -> 4]);
//        tile T+2 @p7 VMC(4) (conv ops older than p3 => unaffected).
// Conv W(i+1): p2 stores prev 2 chunks (loads retired by prev p7 VMC(4)) + loads 2.

#define VMC(N) asm volatile("s_waitcnt vmcnt(" #N ")" ::: "memory")

#define STAGE_A(T, H)                                                          \
  { load_lds16(Asrc0 + (size_t)((H) * 128) * Kdim + (T) * 64,                  \
               ldsA + ((T) & 1) * 16384 + (H) * 8192 + tid * 8);               \
    load_lds16(Asrc0 + (size_t)((H) * 128 + 64) * Kdim + (T) * 64,             \
               ldsA + ((T) & 1) * 16384 + (H) * 8192 + 4096 + tid * 8); }

#define STAGE_B(T, H)                                                          \
  { load_lds16(Bsrc0 + (size_t)((H) * 128) * Kdim + (T) * 64,                  \
               ldsB + ((T) & 1) * 16384 + (H) * 8192 + tid * 8);               \
    load_lds16(Bsrc0 + (size_t)((H) * 128 + 64) * Kdim + (T) * 64,             \
               ldsB + ((T) & 1) * 16384 + (H) * 8192 + 4096 + tid * 8); }

#define CVSTORE(SRC, CIDX)                                                     \
  { u16x4 o_;                                                                  \
    o_[0] = bf16_rn(SRC[0]); o_[1] = bf16_rn(SRC[1]);                          \
    o_[2] = bf16_rn(SRC[2]); o_[3] = bf16_rn(SRC[3]);                          \
    *(u16x4*)(Wnd + cvoff + (size_t)(CIDX) * 2048) = o_; }

// p2 conv body: stores of chunks loaded last group, then this group's 2 loads
#define CONVP2                                                                 \
  { if (CONVON && t >= 1 && t <= 16) {                                         \
      __builtin_amdgcn_sched_barrier(0);                                       \
      CVSTORE(cvA, 2 * (t - 1))                                                \
      CVSTORE(cvB, 2 * (t - 1) + 1)                                            \
    }                                                                          \
    if (CONVON && t < 16) {                                                    \
      const float* cpa_ = Wns + cvoff + (size_t)(2 * t) * 2048;                \
      const float* cpb_ = Wns + cvoff + (size_t)(2 * t + 1) * 2048;            \
      asm volatile("global_load_dwordx4 %0, %2, off\n\t"                       \
                   "global_load_dwordx4 %1, %3, off"                           \
                   : "=&v"(cvA), "=&v"(cvB) : "v"(cpa_), "v"(cpb_)             \
                   : "memory");                                                \
    } }

#define VMP3                                                                   \
  { if (CONVON) {                                                              \
      if (t == 0 || t == 16) { VMC(4); }                                       \
      else if (t < 16)       { VMC(6); }                                       \
      else                   { VMC(2); }                                       \
    } else { VMC(2); } }

#define PH1(KT, MH, NH, STAGE_STMT, VM_STMT)                                   \
  {                                                                            \
    const u16* Ab = ldsA + ((KT) & 1) * 16384 + aBase + (MH) * 4096;           \
    const u16* Bb = ldsB + ((KT) & 1) * 16384 + bBase + (NH) * 2048;           \
    if ((NH) == 0) {                                                           \
      _Pragma("unroll") for (int mi = 0; mi < 4; ++mi) {                       \
        afr[mi][0] = *(const short8*)(Ab + mi * 1024 + gk0);                   \
        afr[mi][1] = *(const short8*)(Ab + mi * 1024 + gk1);                   \
      }                                                                        \
    }                                                                          \
    if ((MH) == 0) {                                                           \
      _Pragma("unroll") for (int ni = 0; ni < 2; ++ni) {                       \
        bfr[NH][ni][0] = *(const short8*)(Bb + ni * 1024 + gk0);               \
        bfr[NH][ni][1] = *(const short8*)(Bb + ni * 1024 + gk1);               \
      }                                                                        \
    }                                                                          \
    STAGE_STMT;                                                                \
    if ((NH) == 0 && (MH) == 0)                                                \
      asm volatile("s_waitcnt lgkmcnt(8)" ::: "memory");                       \
    VM_STMT;                                                                   \
    __builtin_amdgcn_s_barrier();                                              \
    asm volatile("s_waitcnt lgkmcnt(0)" ::: "memory");                         \
    __builtin_amdgcn_sched_barrier(0);                                         \
    __builtin_amdgcn_s_setprio(1);                                             \
    _Pragma("unroll") for (int mi = 0; mi < 4; ++mi)                           \
      _Pragma("unroll") for (int ni = 0; ni < 2; ++ni) {                       \
        acc[(MH) * 4 + mi][(NH) * 2 + ni] =                                    \
          __builtin_amdgcn_mfma_f32_16x16x32_bf16(afr[mi][0], bfr[NH][ni][0],  \
            acc[(MH) * 4 + mi][(NH) * 2 + ni], 0, 0, 0);                       \
        acc[(MH) * 4 + mi][(NH) * 2 + ni] =                                    \
          __builtin_amdgcn_mfma_f32_16x16x32_bf16(afr[mi][1], bfr[NH][ni][1],  \
            acc[(MH) * 4 + mi][(NH) * 2 + ni], 0, 0, 0);                       \
      }                                                                        \
    __builtin_amdgcn_s_setprio(0);                                             \
  }

template <bool OUTF32, bool CONVON>
__global__ __launch_bounds__(512, 2) void gemm256_kernel(const u16* __restrict__ A,
                                                         const u16* __restrict__ B,
                                                         const float* __restrict__ bias,
                                                         const float* __restrict__ slope,
                                                         void* __restrict__ Cv,
                                                         const float* __restrict__ Wns,
                                                         u16* __restrict__ Wnd) {
  constexpr int Kdim = NNODES;
  __shared__ u16 lds[65536];           // 128KB: A [0,32768), B [32768,65536)
  u16* ldsA = lds;
  u16* ldsB = lds + 32768;

  const int tid  = threadIdx.x;
  const int lane = tid & 63;
  const int wid  = tid >> 6;
  const int wr   = wid >> 2;           // 0..1 : 128-row half
  const int wc   = wid & 3;            // 0..3 : 64-col quarter

  // XCD-aware bijective swizzle (256 blocks, 8 XCDs)
  int bid = blockIdx.x;
  int swz = (bid & 7) * 32 + (bid >> 3);
  const int brow = (swz >> 4) * 256;
  const int bcol = (swz & 15) * 256;

  // staging source: thread t -> row t/8, granule (t&7) XOR (row&7)  (pre-swizzled)
  const int srow = tid >> 3;
  const int sg   = ((tid & 7) ^ (srow & 7)) * 8;
  const u16* Asrc0 = A + (size_t)(brow + srow) * Kdim + sg;
  const u16* Bsrc0 = B + (size_t)(bcol + srow) * Kdim + sg;

  // ds_read: lane -> row r16, k-quarter kq; granule g = (ks*4+kq) ^ (r16&7)
  const int r16 = lane & 15, kq = lane >> 4;
  const int g0  = kq ^ (r16 & 7);
  const int gk0 = g0 * 8, gk1 = (g0 ^ 4) * 8;
  const int aBase = wr * 8192 + r16 * 64;
  const int bBase = (wc >> 1) * 8192 + ((wc & 1) * 64 + r16) * 64;

  // W(i+1) conversion: block bid converts 64K f32 (32 chunks x 512thr x float4)
  const size_t cvoff = (size_t)bid * 65536 + tid * 4;
  f32x4 cvA, cvB;

  f32x4 acc[8][4] = {};
  short8 afr[4][2], bfr[2][2][2];

  // prologue: stage B(0), A(0), B(1); VMC(4) certifies tiles' A(0),B(0)
  STAGE_B(0, 0) STAGE_B(0, 1) STAGE_A(0, 0) STAGE_A(0, 1) STAGE_B(1, 0) STAGE_B(1, 1)
  VMC(4);
  __builtin_amdgcn_s_barrier();

  for (int t = 0; t < 31; ++t) {
    const int T = 2 * t;
    PH1(T,     0, 0, STAGE_A(T + 1, 0), ;)
    PH1(T,     0, 1, STAGE_A(T + 1, 1), ;)
    PH1(T,     1, 0, CONVP2,            ;)
    PH1(T,     1, 1, STAGE_B(T + 2, 0), VMP3)
    PH1(T + 1, 0, 0, STAGE_B(T + 2, 1), ;)
    PH1(T + 1, 0, 1, STAGE_A(T + 2, 0), ;)
    PH1(T + 1, 1, 0, STAGE_A(T + 2, 1), ;)
    PH1(T + 1, 1, 1, { STAGE_B(T + 3, 0) STAGE_B(T + 3, 1) }, VMC(4))
  }
  // tail: tiles 62,63 (A(63) staged p0,p1; VMC(0) certifies tile 63)
  PH1(62, 0, 0, STAGE_A(63, 0), ;)
  PH1(62, 0, 1, STAGE_A(63, 1), ;)
  PH1(62, 1, 0, ;, ;)
  PH1(62, 1, 1, ;, VMC(0))
  PH1(63, 0, 0, ;, ;)
  PH1(63, 0, 1, ;, ;)
  PH1(63, 1, 0, ;, ;)
  PH1(63, 1, 1, ;, ;)

  // epilogue: bias + per-feature LeakyReLU
  const int crow0 = brow + wr * 128 + (lane >> 4) * 4;
  const int ccol0 = bcol + wc * 64 + r16;
#pragma unroll
  for (int n = 0; n < 4; ++n) {
    int col = ccol0 + n * 16;
    float bv = bias[col], sv = slope[col];
#pragma unroll
    for (int m = 0; m < 8; ++m) {
      int row0 = crow0 + m * 16;
#pragma unroll
      for (int r = 0; r < 4; ++r) {
        float vv = acc[m][n][r] + bv;
        vv = vv < 0.f ? vv * sv : vv;
        if constexpr (OUTF32) {
          ((float*)Cv)[(size_t)(row0 + r) * NNODES + col] = vv;
        } else {
          ((u16*)Cv)[(size_t)(row0 + r) * NNODES + col] = bf16_rn(vv);
        }
      }
    }
  }
}

extern "C" void kernel_launch(void* const* d_in, const int* in_sizes, int n_in,
                              void* d_out, int out_size, void* d_ws, size_t ws_size,
                              hipStream_t stream) {
  const float* x     = (const float*)d_in[0];
  const float* ln_g  = (const float*)d_in[1];
  const float* ln_b  = (const float*)d_in[2];
  const float* W     = (const float*)d_in[3];
  const float* b     = (const float*)d_in[4];
  const float* slope = (const float*)d_in[5];
  float* out = (float*)d_out;

  char* ws = (char*)d_ws;
  u16* Wbuf0 = (u16*)ws;                                   // 32 MB
  u16* Wbuf1 = (u16*)(ws + (size_t)32 * 1024 * 1024);      // 32 MB
  u16* lnbuf = (u16*)(ws + (size_t)64 * 1024 * 1024);      // 32 MB
  u16* ybuf  = (u16*)(ws + (size_t)96 * 1024 * 1024);      // 32 MB (bf16 y)

  const size_t WN = (size_t)NNODES * NNODES;

  for (int i = 0; i < NBLK; ++i) {
    u16* Wc = (i & 1) ? Wbuf1 : Wbuf0;
    u16* Wn = (i & 1) ? Wbuf0 : Wbuf1;
    if (i == 0)
      prep_kernel<<<dim3(16384 + NBATCH), dim3(256), 0, stream>>>(
          W, Wbuf0, x, ln_g, ln_b, lnbuf);
    else
      ln_bf16_kernel<<<dim3(NBATCH), dim3(256), 0, stream>>>(
          ybuf, ln_g + (size_t)i * NNODES, ln_b + (size_t)i * NNODES, lnbuf);

    if (i == NBLK - 1)
      gemm256_kernel<true, false><<<dim3(256), dim3(512), 0, stream>>>(
          lnbuf, Wc, b + (size_t)i * NNODES, slope + (size_t)i * NNODES,
          (void*)out, nullptr, nullptr);
    else
      gemm256_kernel<false, true><<<dim3(256), dim3(512), 0, stream>>>(
          lnbuf, Wc, b + (size_t)i * NNODES, slope + (size_t)i * NNODES,
          (void*)ybuf, W + WN * (i + 1), Wn);
  }
}